// Round 4
// baseline (237.365 us; speedup 1.0000x reference)
//
#include <hip/hip_runtime.h>

// SoftNormalShader: fused normal_shading + softmax_rgb_blend
// Layout R4: 2 lanes per pixel, 4 fragments per lane. ALL loads are
// unconditional (branch-free): inactive fragments gather face 0 (wave
// broadcast) and their contribution is annihilated by w==0.0f exactly.
// This removes the 4x serialized divergent gather-latency chains of R3.
// N=4, H=512, W=512, K=8, V=50000, F=100000

constexpr int   N_PIX      = 4 * 512 * 512;
constexpr float INV_SIGMA  = 1.0f / 1e-4f;
constexpr float INV_GAMMA  = 1.0f / 1e-4f;
constexpr float ZFARV      = 100.0f;
constexpr float INV_ZRANGE = 1.0f / 99.0f;   // 1/(ZFAR-ZNEAR)
constexpr float EPSV       = 1e-10f;

// Prepass: pack gathered vertex normals per face into a 48B row
// (4.8MB table, L3-resident) so the hot kernel does 3x dwordx4 gathers
// instead of 12x dependent dword gathers per fragment.
__global__ __launch_bounds__(256)
void build_face_normals_kernel(const float* __restrict__ vn,
                               const int*   __restrict__ faces,
                               float*       __restrict__ fn,
                               int nf)
{
    int f = blockIdx.x * blockDim.x + threadIdx.x;
    if (f >= nf) return;
    int v0 = faces[3 * f + 0];
    int v1 = faces[3 * f + 1];
    int v2 = faces[3 * f + 2];
    const float* p0 = vn + 3 * (size_t)v0;
    const float* p1 = vn + 3 * (size_t)v1;
    const float* p2 = vn + 3 * (size_t)v2;
    float4 r0 = make_float4(p0[0], p0[1], p0[2], p1[0]);
    float4 r1 = make_float4(p1[1], p1[2], p2[0], p2[1]);
    float4 r2 = make_float4(p2[2], 0.f, 0.f, 0.f);
    float4* dst = reinterpret_cast<float4*>(fn + 12 * (size_t)f);
    dst[0] = r0; dst[1] = r1; dst[2] = r2;
}

__global__ __launch_bounds__(256)
void shade_kernel(const float* __restrict__ bary,
                  const float* __restrict__ dists,
                  const float* __restrict__ zbuf,
                  const int*   __restrict__ p2f,
                  const float* __restrict__ fn,     // packed table (or null)
                  const float* __restrict__ vn,     // fallback path
                  const int*   __restrict__ faces,  // fallback path
                  float*       __restrict__ out)
{
    int gid = blockIdx.x * blockDim.x + threadIdx.x;  // 2 threads per pixel
    int h   = gid & 1;                                 // half: k = 4h..4h+3
    int pix = gid >> 1;
    if (pix >= N_PIX) return;

    // Dense streaming loads: 16B/lane d/z/f + 48B/lane bary, all coalesced.
    float4 d4 = reinterpret_cast<const float4*>(dists)[gid];
    float4 z4 = reinterpret_cast<const float4*>(zbuf)[gid];
    int4   f4 = reinterpret_cast<const int4*>(p2f)[gid];
    const float4* bp = reinterpret_cast<const float4*>(bary) + 3 * (size_t)gid;
    float4 b0 = bp[0], b1 = bp[1], b2 = bp[2];

    float dk[4] = {d4.x, d4.y, d4.z, d4.w};
    float zk[4] = {z4.x, z4.y, z4.z, z4.w};
    int   fk[4] = {f4.x, f4.y, f4.z, f4.w};
    float bf[12] = {b0.x, b0.y, b0.z, b0.w, b1.x, b1.y, b1.z, b1.w,
                    b2.x, b2.y, b2.z, b2.w};

    float pr[4], zi[4];
#pragma unroll
    for (int k = 0; k < 4; ++k) {
        bool m = fk[k] >= 0;
        // sigmoid(-d/sigma) = 1/(1+exp(d/sigma))
        pr[k] = m ? __builtin_amdgcn_rcpf(1.0f + __expf(dk[k] * INV_SIGMA)) : 0.0f;
        zi[k] = m ? (ZFARV - zk[k]) * INV_ZRANGE : 0.0f;
    }

    // Per-pixel max of z_inv: in-register tree + one cross-lane exchange.
    float zmax = fmaxf(fmaxf(zi[0], zi[1]), fmaxf(zi[2], zi[3]));
    zmax = fmaxf(zmax, __shfl_xor(zmax, 1));

    // alpha = prod(1 - prob)
    float am = (1.0f - pr[0]) * (1.0f - pr[1]) * (1.0f - pr[2]) * (1.0f - pr[3]);
    am *= __shfl_xor(am, 1);

    // Softmax weights; pick gather index branch-free (inactive -> face 0,
    // wave-broadcast line; contribution exactly zeroed by w==0).
    float w[4];
    int   fe[4];
#pragma unroll
    for (int k = 0; k < 4; ++k) {
        w[k]  = pr[k] * __expf((zi[k] - zmax) * INV_GAMMA);
        fe[k] = (w[k] != 0.0f) ? fk[k] : 0;
    }

    // Issue ALL gathers back-to-back (single waitcnt region, max MLP).
    float4 r0[4], r1[4], r2[4];
    if (fn) {
#pragma unroll
        for (int k = 0; k < 4; ++k) {
            const float4* p = reinterpret_cast<const float4*>(fn + 12 * (size_t)fe[k]);
            r0[k] = p[0]; r1[k] = p[1]; r2[k] = p[2];
        }
    } else {
#pragma unroll
        for (int k = 0; k < 4; ++k) {
            int v0 = faces[3 * fe[k] + 0];
            int v1 = faces[3 * fe[k] + 1];
            int v2 = faces[3 * fe[k] + 2];
            r0[k] = make_float4(vn[3 * v0 + 0], vn[3 * v0 + 1], vn[3 * v0 + 2], vn[3 * v1 + 0]);
            r1[k] = make_float4(vn[3 * v1 + 1], vn[3 * v1 + 2], vn[3 * v2 + 0], vn[3 * v2 + 1]);
            r2[k] = make_float4(vn[3 * v2 + 2], 0.f, 0.f, 0.f);
        }
    }

    float ws = 0.0f, cr = 0.0f, cg = 0.0f, cb = 0.0f;
#pragma unroll
    for (int k = 0; k < 4; ++k) {
        float bw0 = bf[3 * k + 0], bw1 = bf[3 * k + 1], bw2 = bf[3 * k + 2];
        ws += w[k];
        cr += w[k] * (bw0 * r0[k].x + bw1 * r0[k].w + bw2 * r1[k].z);
        cg += w[k] * (bw0 * r0[k].y + bw1 * r1[k].x + bw2 * r1[k].w);
        cb += w[k] * (bw0 * r0[k].z + bw1 * r1[k].y + bw2 * r2[k].x);
    }

    // Cross-lane pair reduction (lane 2p <-> 2p+1).
    ws += __shfl_xor(ws, 1);
    cr += __shfl_xor(cr, 1);
    cg += __shfl_xor(cg, 1);
    cb += __shfl_xor(cb, 1);

    if (h == 0) {
        float delta     = fmaxf(__expf((EPSV - zmax) * INV_GAMMA), EPSV);
        float inv_denom = __builtin_amdgcn_rcpf(ws + delta);
        float4 o;
        o.x = (cr + delta) * inv_denom;   // background = (1,1,1)
        o.y = (cg + delta) * inv_denom;
        o.z = (cb + delta) * inv_denom;
        o.w = 1.0f - am;
        // Even lanes write 32 consecutive float4 -> dense 512B per wave.
        reinterpret_cast<float4*>(out)[pix] = o;
    }
}

extern "C" void kernel_launch(void* const* d_in, const int* in_sizes, int n_in,
                              void* d_out, int out_size, void* d_ws, size_t ws_size,
                              hipStream_t stream) {
    const float* vn    = (const float*)d_in[0];
    const float* bary  = (const float*)d_in[1];
    const float* dists = (const float*)d_in[2];
    const float* zbuf  = (const float*)d_in[3];
    const int*   faces = (const int*)d_in[4];
    const int*   p2f   = (const int*)d_in[5];
    float*       out   = (float*)d_out;

    int nf = in_sizes[4] / 3;

    float* fn = nullptr;
    size_t need = (size_t)nf * 12 * sizeof(float);
    if (ws_size >= need) {
        fn = (float*)d_ws;
        build_face_normals_kernel<<<(nf + 255) / 256, 256, 0, stream>>>(vn, faces, fn, nf);
    }

    int threads = N_PIX * 2;
    shade_kernel<<<threads / 256, 256, 0, stream>>>(bary, dists, zbuf, p2f,
                                                    fn, vn, faces, out);
}

// Round 5
// 232.738 us; speedup vs baseline: 1.0199x; 1.0199x over previous
//
#include <hip/hip_runtime.h>
#include <hip/hip_fp16.h>

// SoftNormalShader: fused normal_shading + softmax_rgb_blend
// Layout R5: lane-per-fragment (R2) + grid-stride with register
// double-buffered prefetch so every wave keeps a streaming burst in
// flight continuously (fix for the ~2.2 TB/s plateau of R1-R4).
// Face-normal table packed to 9xfp16 in 32B rows: 3.2MB, L2-resident.
// N=4, H=512, W=512, K=8, V=50000, F=100000

constexpr int   N_PIX      = 4 * 512 * 512;
constexpr int   N_FRAG     = N_PIX * 8;          // 8388608
constexpr int   N_BLOCKS   = 2048;
constexpr int   N_THREADS  = N_BLOCKS * 256;     // 524288
constexpr int   N_ITERS    = N_FRAG / N_THREADS; // 16
constexpr float INV_SIGMA  = 1.0f / 1e-4f;
constexpr float INV_GAMMA  = 1.0f / 1e-4f;
constexpr float ZFARV      = 100.0f;
constexpr float INV_ZRANGE = 1.0f / 99.0f;       // 1/(ZFAR-ZNEAR)
constexpr float EPSV       = 1e-10f;

// Prepass: gather vertex normals per face, convert to fp16, pack 9 halves
// into a 32B-aligned row. Table = F*32B = 3.2MB -> fits a single XCD L2.
__global__ __launch_bounds__(256)
void build_face_normals_kernel(const float* __restrict__ vn,
                               const int*   __restrict__ faces,
                               __half*      __restrict__ fnh,
                               int nf)
{
    int f = blockIdx.x * blockDim.x + threadIdx.x;
    if (f >= nf) return;
    int v0 = faces[3 * f + 0];
    int v1 = faces[3 * f + 1];
    int v2 = faces[3 * f + 2];
    union { ushort us[16]; uint4 u4[2]; } row;
    row.us[0] = __half_as_ushort(__float2half(vn[3 * v0 + 0]));
    row.us[1] = __half_as_ushort(__float2half(vn[3 * v0 + 1]));
    row.us[2] = __half_as_ushort(__float2half(vn[3 * v0 + 2]));
    row.us[3] = __half_as_ushort(__float2half(vn[3 * v1 + 0]));
    row.us[4] = __half_as_ushort(__float2half(vn[3 * v1 + 1]));
    row.us[5] = __half_as_ushort(__float2half(vn[3 * v1 + 2]));
    row.us[6] = __half_as_ushort(__float2half(vn[3 * v2 + 0]));
    row.us[7] = __half_as_ushort(__float2half(vn[3 * v2 + 1]));
    row.us[8] = __half_as_ushort(__float2half(vn[3 * v2 + 2]));
    row.us[9] = 0; row.us[10] = 0; row.us[11] = 0;
    row.us[12] = 0; row.us[13] = 0; row.us[14] = 0; row.us[15] = 0;
    uint4* dst = reinterpret_cast<uint4*>(fnh + 16 * (size_t)f);
    dst[0] = row.u4[0];
    dst[1] = row.u4[1];
}

__global__ __launch_bounds__(256, 8)
void shade_kernel(const float*  __restrict__ bary,
                  const float*  __restrict__ dists,
                  const float*  __restrict__ zbuf,
                  const int*    __restrict__ p2f,
                  const __half* __restrict__ fnh,
                  float*        __restrict__ out)
{
    int gid = blockIdx.x * 256 + threadIdx.x;
    int kk  = threadIdx.x & 7;          // fragment slot within pixel (stride keeps it)

    // Preload iteration 0's streaming data.
    float nd  = dists[gid];
    float nz  = zbuf[gid];
    int   nf_ = p2f[gid];
    size_t nbo = 3 * (size_t)gid;
    float nb0 = bary[nbo + 0];
    float nb1 = bary[nbo + 1];
    float nb2 = bary[nbo + 2];

#pragma unroll
    for (int it = 0; it < N_ITERS; ++it) {
        // Grab current iteration's values.
        float d  = nd, zb = nz;
        int   f  = nf_;
        float b0 = nb0, b1 = nb1, b2 = nb2;

        // Immediately issue NEXT iteration's streaming burst (24B/lane,
        // dense): it stays in flight while we process the current one.
        int gn = gid + N_THREADS;
        if (it + 1 < N_ITERS) {
            nd  = dists[gn];
            nz  = zbuf[gn];
            nf_ = p2f[gn];
            size_t bo = 3 * (size_t)gn;
            nb0 = bary[bo + 0];
            nb1 = bary[bo + 1];
            nb2 = bary[bo + 2];
        }

        bool  m  = f >= 0;
        // sigmoid(-d/sigma) = 1/(1+exp(d/sigma))
        float pr = m ? __builtin_amdgcn_rcpf(1.0f + __expf(d * INV_SIGMA)) : 0.0f;
        float zi = m ? (ZFARV - zb) * INV_ZRANGE : 0.0f;

        // 8-lane butterfly reductions (masks 1,2,4 stay inside k-group).
        float zmax = zi;
        zmax = fmaxf(zmax, __shfl_xor(zmax, 1));
        zmax = fmaxf(zmax, __shfl_xor(zmax, 2));
        zmax = fmaxf(zmax, __shfl_xor(zmax, 4));

        float am = 1.0f - pr;           // alpha = prod(1 - prob)
        am *= __shfl_xor(am, 1);
        am *= __shfl_xor(am, 2);
        am *= __shfl_xor(am, 4);

        // Softmax weight; underflows to exactly 0 unless zi within ~0.0087
        // of zmax (gamma=1e-4) -> typically ~1 active lane per pixel.
        float w  = pr * __expf((zi - zmax) * INV_GAMMA);
        int   fe = (w != 0.0f) ? f : 0;   // inactive -> face 0 (broadcast line)

        // Gather packed fp16 normals (L2-resident 3.2MB table), branch-free.
        const __half* hp = fnh + 16 * (size_t)fe;
        uint4 a  = *reinterpret_cast<const uint4*>(hp);
        uint  b8 = reinterpret_cast<const uint*>(hp)[4];
        float2 q0 = __half22float2(*reinterpret_cast<const __half2*>(&a.x)); // n0x n0y
        float2 q1 = __half22float2(*reinterpret_cast<const __half2*>(&a.y)); // n0z n1x
        float2 q2 = __half22float2(*reinterpret_cast<const __half2*>(&a.z)); // n1y n1z
        float2 q3 = __half22float2(*reinterpret_cast<const __half2*>(&a.w)); // n2x n2y
        float2 q4 = __half22float2(*reinterpret_cast<const __half2*>(&b8));  // n2z --

        // Contribution annihilated exactly by w==0 for inactive lanes.
        float cr = w * (b0 * q0.x + b1 * q1.y + b2 * q3.x);
        float cg = w * (b0 * q0.y + b1 * q2.x + b2 * q3.y);
        float cb = w * (b0 * q1.x + b1 * q2.y + b2 * q4.x);
        float ws = w;

        ws += __shfl_xor(ws, 1);  cr += __shfl_xor(cr, 1);
        cg += __shfl_xor(cg, 1);  cb += __shfl_xor(cb, 1);
        ws += __shfl_xor(ws, 2);  cr += __shfl_xor(cr, 2);
        cg += __shfl_xor(cg, 2);  cb += __shfl_xor(cb, 2);
        ws += __shfl_xor(ws, 4);  cr += __shfl_xor(cr, 4);
        cg += __shfl_xor(cg, 4);  cb += __shfl_xor(cb, 4);

        if (kk == 0) {
            float delta     = fmaxf(__expf((EPSV - zmax) * INV_GAMMA), EPSV);
            float inv_denom = __builtin_amdgcn_rcpf(ws + delta);
            float4 o;
            o.x = (cr + delta) * inv_denom;   // background = (1,1,1)
            o.y = (cg + delta) * inv_denom;
            o.z = (cb + delta) * inv_denom;
            o.w = 1.0f - am;
            // 8 storing lanes per wave -> 128B contiguous per wave-iter.
            reinterpret_cast<float4*>(out)[gid >> 3] = o;
        }
        gid = gn;
    }
}

extern "C" void kernel_launch(void* const* d_in, const int* in_sizes, int n_in,
                              void* d_out, int out_size, void* d_ws, size_t ws_size,
                              hipStream_t stream) {
    const float* vn    = (const float*)d_in[0];
    const float* bary  = (const float*)d_in[1];
    const float* dists = (const float*)d_in[2];
    const float* zbuf  = (const float*)d_in[3];
    const int*   faces = (const int*)d_in[4];
    const int*   p2f   = (const int*)d_in[5];
    float*       out   = (float*)d_out;

    int nf = in_sizes[4] / 3;
    __half* fnh = (__half*)d_ws;   // nf*32B = 3.2MB, ws is at least this big

    build_face_normals_kernel<<<(nf + 255) / 256, 256, 0, stream>>>(vn, faces, fnh, nf);
    shade_kernel<<<N_BLOCKS, 256, 0, stream>>>(bary, dists, zbuf, p2f, fnh, out);
}